// Round 5
// baseline (134.301 us; speedup 1.0000x reference)
//
#include <hip/hip_runtime.h>

// out = x * exp(betas), betas broadcast over 512 (b*c) planes.
// R5: keep nt hints (R4 ablation: removing them cost +9us) + hoisted exp.
// New: 32B per thread (2 consecutive float4) -> 2KB contiguous burst per
// wave access; block=512, grid=1024 -> 8192 waves = exactly 32/CU, single
// resident occupancy batch (previously 64/CU in 2 batches).

typedef float f32x4 __attribute__((ext_vector_type(4)));

__global__ __launch_bounds__(512) void diag_exp_scale_w2(
    const f32x4* __restrict__ xr4,
    const f32x4* __restrict__ xi4,
    const f32x4* __restrict__ br4,
    const f32x4* __restrict__ bi4,
    f32x4* __restrict__ outr4,
    f32x4* __restrict__ outi4,
    int hw4,               // (h*w)/4 = 16384, power of two
    int planes_per_group,  // 16
    int nplanes,           // b*c = 512
    int blocks_per_tensor) // grid split point
{
    int blk = blockIdx.x;
    const f32x4* __restrict__ x;
    const f32x4* __restrict__ bet;
    f32x4* __restrict__ o;
    if (blk < blocks_per_tensor) {        // uniform per-block branch
        x = xr4;  bet = br4;  o = outr4;
    } else {
        x = xi4;  bet = bi4;  o = outi4;
        blk -= blocks_per_tensor;
    }

    int hw8 = hw4 >> 1;                   // pair-columns per plane (8192)
    int t  = blk * blockDim.x + threadIdx.x;
    int mp = t & (hw8 - 1);               // pair-column owned by this thread
    int g  = t / hw8;                     // plane group
    int m  = mp << 1;                     // float4 column (even)

    // Hoisted loop-invariant scale: 2 L2 loads + 8 expf per thread.
    f32x4 s0 = bet[m];
    f32x4 s1 = bet[m + 1];
    s0.x = __expf(s0.x); s0.y = __expf(s0.y);
    s0.z = __expf(s0.z); s0.w = __expf(s0.w);
    s1.x = __expf(s1.x); s1.y = __expf(s1.y);
    s1.z = __expf(s1.z); s1.w = __expf(s1.w);

    int p0 = g * planes_per_group;
    int p1 = p0 + planes_per_group;
    if (p1 > nplanes) p1 = nplanes;

    #pragma unroll 4
    for (int p = p0; p < p1; ++p) {
        int idx = p * hw4 + m;            // max 8.4M, fits int
        f32x4 v0 = __builtin_nontemporal_load(&x[idx]);
        f32x4 v1 = __builtin_nontemporal_load(&x[idx + 1]);
        __builtin_nontemporal_store(v0 * s0, &o[idx]);
        __builtin_nontemporal_store(v1 * s1, &o[idx + 1]);
    }
}

extern "C" void kernel_launch(void* const* d_in, const int* in_sizes, int n_in,
                              void* d_out, int out_size, void* d_ws, size_t ws_size,
                              hipStream_t stream) {
    const float* xr = (const float*)d_in[0];   // x_real  (b*c*h*w)
    const float* xi = (const float*)d_in[1];   // x_imag
    const float* br = (const float*)d_in[2];   // betas_real (h*w)
    const float* bi = (const float*)d_in[3];   // betas_imag

    float* out = (float*)d_out;
    int n    = in_sizes[0];        // 33,554,432
    int hw   = in_sizes[2];        // 65,536
    int hw4  = hw >> 2;            // 16,384
    int hw8  = hw4 >> 1;           // 8,192
    int nplanes = n / hw;          // 512

    float* outr = out;             // tuple concat: out_real then out_imag
    float* outi = out + n;

    const int threads = 512;
    const int ngroups = 32;                         // 32 x 16 planes = 512
    int planes_per_group = (nplanes + ngroups - 1) / ngroups;
    int threads_per_tensor = hw8 * ngroups;         // 262,144
    int blocks_per_tensor = threads_per_tensor / threads;  // 512
    int blocks = blocks_per_tensor * 2;             // 1024 -> 8192 waves = 32/CU

    diag_exp_scale_w2<<<blocks, threads, 0, stream>>>(
        (const f32x4*)xr, (const f32x4*)xi,
        (const f32x4*)br, (const f32x4*)bi,
        (f32x4*)outr, (f32x4*)outi,
        hw4, planes_per_group, nplanes, blocks_per_tensor);
}

// Round 6
// 104.547 us; speedup vs baseline: 1.2846x; 1.2846x over previous
//
#include <hip/hip_runtime.h>

// out = x * exp(betas), betas broadcast over 512 (b*c) planes.
// R6: paired-column version with CORRECT coalescing (R5 broke it with
// stride-2 lanes). Wave W owns 128 consecutive float4 columns: lane reads
// c0 = mw*128+lane and c1 = c0+64 -> each load instruction is a dense
// contiguous 1KB wave access. 8192 waves total = exactly 32/CU, single
// occupancy batch. Keep: nt hints (R4: +9us), hoisted exp, tensor-split.

typedef float f32x4 __attribute__((ext_vector_type(4)));

__global__ __launch_bounds__(256) void diag_exp_scale_pair(
    const f32x4* __restrict__ xr4,
    const f32x4* __restrict__ xi4,
    const f32x4* __restrict__ br4,
    const f32x4* __restrict__ bi4,
    f32x4* __restrict__ outr4,
    f32x4* __restrict__ outi4,
    int hw4,               // (h*w)/4 = 16384, power of two
    int planes_per_group,  // 16
    int nplanes,           // b*c = 512
    int blocks_per_tensor) // grid split point
{
    int blk = blockIdx.x;
    const f32x4* __restrict__ x;
    const f32x4* __restrict__ bet;
    f32x4* __restrict__ o;
    if (blk < blocks_per_tensor) {        // uniform per-block branch
        x = xr4;  bet = br4;  o = outr4;
    } else {
        x = xi4;  bet = bi4;  o = outi4;
        blk -= blocks_per_tensor;
    }

    int t    = blk * blockDim.x + threadIdx.x;
    int lane = t & 63;
    int W    = t >> 6;                    // wave index within tensor
    int wavesPerPlane = hw4 >> 7;         // 128 columns/wave -> 128 waves/plane
    int mw   = W & (wavesPerPlane - 1);   // wave slot within plane columns
    int g    = W / wavesPerPlane;         // plane group

    int c0 = mw * 128 + lane;             // contiguous 1KB across wave
    int c1 = c0 + 64;                     // second contiguous 1KB

    // Hoisted loop-invariant scales: 2 L2 loads + 8 expf per thread.
    f32x4 s0 = bet[c0];
    f32x4 s1 = bet[c1];
    s0.x = __expf(s0.x); s0.y = __expf(s0.y);
    s0.z = __expf(s0.z); s0.w = __expf(s0.w);
    s1.x = __expf(s1.x); s1.y = __expf(s1.y);
    s1.z = __expf(s1.z); s1.w = __expf(s1.w);

    int p0 = g * planes_per_group;
    int p1 = p0 + planes_per_group;
    if (p1 > nplanes) p1 = nplanes;

    #pragma unroll 4
    for (int p = p0; p < p1; ++p) {
        int idx = p * hw4;                // max 8.4M, fits int
        f32x4 v0 = __builtin_nontemporal_load(&x[idx + c0]);
        f32x4 v1 = __builtin_nontemporal_load(&x[idx + c1]);
        __builtin_nontemporal_store(v0 * s0, &o[idx + c0]);
        __builtin_nontemporal_store(v1 * s1, &o[idx + c1]);
    }
}

extern "C" void kernel_launch(void* const* d_in, const int* in_sizes, int n_in,
                              void* d_out, int out_size, void* d_ws, size_t ws_size,
                              hipStream_t stream) {
    const float* xr = (const float*)d_in[0];   // x_real  (b*c*h*w)
    const float* xi = (const float*)d_in[1];   // x_imag
    const float* br = (const float*)d_in[2];   // betas_real (h*w)
    const float* bi = (const float*)d_in[3];   // betas_imag

    float* out = (float*)d_out;
    int n    = in_sizes[0];        // 33,554,432
    int hw   = in_sizes[2];        // 65,536
    int hw4  = hw >> 2;            // 16,384
    int nplanes = n / hw;          // 512

    float* outr = out;             // tuple concat: out_real then out_imag
    float* outi = out + n;

    const int threads = 256;
    const int ngroups = 32;        // 32 groups x 16 planes = 512 planes
    int planes_per_group = (nplanes + ngroups - 1) / ngroups;
    // waves/tensor = (hw4/128) * ngroups = 128*32 = 4096 -> threads = 262144
    int threads_per_tensor = (hw4 >> 7) * ngroups * 64;
    int blocks_per_tensor  = threads_per_tensor / threads;  // 1024
    int blocks = blocks_per_tensor * 2;  // 2048 -> 8192 waves = 32/CU, 1 batch

    diag_exp_scale_pair<<<blocks, threads, 0, stream>>>(
        (const f32x4*)xr, (const f32x4*)xi,
        (const f32x4*)br, (const f32x4*)bi,
        (f32x4*)outr, (f32x4*)outi,
        hw4, planes_per_group, nplanes, blocks_per_tensor);
}

// Round 7
// 86.024 us; speedup vs baseline: 1.5612x; 1.2153x over previous
//
#include <hip/hip_runtime.h>

// out = x * exp(betas), betas broadcast over 512 (b*c) planes.
// R7 = R3 structure (best: 98us) with nt DECOMPOSED: nontemporal LOADS
// (keep streamed input out of L2) + PLAIN stores (fill kernel shows the
// L2 write-back path drains at 7 TB/s; nt stores may forfeit L2 write
// coalescing). R4 only ever tested removing both together.

typedef float f32x4 __attribute__((ext_vector_type(4)));

__global__ __launch_bounds__(256) void diag_exp_scale_ntload(
    const f32x4* __restrict__ xr4,
    const f32x4* __restrict__ xi4,
    const f32x4* __restrict__ br4,
    const f32x4* __restrict__ bi4,
    f32x4* __restrict__ outr4,
    f32x4* __restrict__ outi4,
    int hw4,               // (h*w)/4 = 16384, power of two
    int planes_per_group,  // 16
    int nplanes,           // b*c = 512
    int blocks_per_tensor) // grid split point
{
    int blk = blockIdx.x;
    const f32x4* __restrict__ x;
    const f32x4* __restrict__ bet;
    f32x4* __restrict__ o;
    if (blk < blocks_per_tensor) {        // uniform per-block branch
        x = xr4;  bet = br4;  o = outr4;
    } else {
        x = xi4;  bet = bi4;  o = outi4;
        blk -= blocks_per_tensor;
    }

    int t = blk * blockDim.x + threadIdx.x;
    int m = t & (hw4 - 1);    // hw column owned by this thread
    int g = t / hw4;          // plane group

    f32x4 s = bet[m];         // one L2 load + 4 expf, hoisted
    s.x = __expf(s.x); s.y = __expf(s.y);
    s.z = __expf(s.z); s.w = __expf(s.w);

    int p0 = g * planes_per_group;
    int p1 = p0 + planes_per_group;
    if (p1 > nplanes) p1 = nplanes;

    #pragma unroll 8
    for (int p = p0; p < p1; ++p) {
        int idx = p * hw4 + m;            // max 8.4M, fits int
        f32x4 v = __builtin_nontemporal_load(&x[idx]);
        o[idx] = v * s;                   // plain store (L2 write-back path)
    }
}

extern "C" void kernel_launch(void* const* d_in, const int* in_sizes, int n_in,
                              void* d_out, int out_size, void* d_ws, size_t ws_size,
                              hipStream_t stream) {
    const float* xr = (const float*)d_in[0];   // x_real  (b*c*h*w)
    const float* xi = (const float*)d_in[1];   // x_imag
    const float* br = (const float*)d_in[2];   // betas_real (h*w)
    const float* bi = (const float*)d_in[3];   // betas_imag

    float* out = (float*)d_out;
    int n    = in_sizes[0];        // 33,554,432
    int hw   = in_sizes[2];        // 65,536
    int hw4  = hw >> 2;            // 16,384
    int nplanes = n / hw;          // 512

    float* outr = out;             // tuple concat: out_real then out_imag
    float* outi = out + n;

    const int threads = 256;
    const int ngroups = 32;                         // 32 x 16 planes = 512
    int planes_per_group = (nplanes + ngroups - 1) / ngroups;
    int threads_per_tensor = hw4 * ngroups;         // 524,288
    int blocks_per_tensor = threads_per_tensor / threads;  // 2048
    int blocks = blocks_per_tensor * 2;             // 4096 -> 64 waves/CU

    diag_exp_scale_ntload<<<blocks, threads, 0, stream>>>(
        (const f32x4*)xr, (const f32x4*)xi,
        (const f32x4*)br, (const f32x4*)bi,
        (f32x4*)outr, (f32x4*)outi,
        hw4, planes_per_group, nplanes, blocks_per_tensor);
}